// Round 13
// baseline (171.401 us; speedup 1.0000x reference)
//
#include <hip/hip_runtime.h>
#include <hip/hip_bf16.h>
#include <stdint.h>

#define BB 4
#define NN 1024
#define DD 1024
#define HH 16
#define HDIM 64
#define KVHH 4
#define MM (BB * NN)  // 4096 token rows

typedef __hip_bfloat16 bf16;
typedef __attribute__((ext_vector_type(8))) short bf16x8;  // 8 bf16 = 4 VGPR
typedef __attribute__((ext_vector_type(4))) short bf16x4;  // 4 bf16 = 2 VGPR
typedef __attribute__((ext_vector_type(4))) float f32x4;

__device__ __forceinline__ float b2f(unsigned short u) {
  return __uint_as_float(((unsigned)u) << 16);
}
__device__ __forceinline__ unsigned short f2b(float x) {
  bf16 h = __float2bfloat16(x);
  unsigned short u;
  __builtin_memcpy(&u, &h, 2);
  return u;
}
__device__ __forceinline__ f32x4 mfma16(bf16x8 a, bf16x8 b, f32x4 c) {
  return __builtin_amdgcn_mfma_f32_16x16x32_bf16(a, b, c, 0, 0, 0);
}
// K=16 MFMA: B-fragment layout (col=l15, k=quad*4+i) matches the K=32 MFMA's
// C layout (col=l15, row=quad*4+r) -> S output feeds PV directly, in-register.
// (Correctness HW-verified r12-r21: absmax identical across all rounds.)
__device__ __forceinline__ f32x4 mfma16k16(bf16x4 a, bf16x4 b, f32x4 c) {
#if __has_builtin(__builtin_amdgcn_mfma_f32_16x16x16bf16_1k)
  return __builtin_amdgcn_mfma_f32_16x16x16bf16_1k(a, b, c, 0, 0, 0);
#else
  asm("s_nop 1\n\tv_mfma_f32_16x16x16_bf16 %0, %1, %2, %0"
      : "+v"(c)
      : "v"(a), "v"(b));
  return c;
#endif
}
__device__ __forceinline__ bf16x4 vlo(bf16x8 v) {
  return __builtin_shufflevector(v, v, 0, 1, 2, 3);
}
__device__ __forceinline__ bf16x4 vhi(bf16x8 v) {
  return __builtin_shufflevector(v, v, 4, 5, 6, 7);
}
__device__ __forceinline__ void gl_lds16(const short* g, short* l) {
  __builtin_amdgcn_global_load_lds(
      (const __attribute__((address_space(1))) unsigned*)g,
      (__attribute__((address_space(3))) unsigned*)l, 16, 0, 0);
}

// ---------------------------------------------------------------------------
// z=0..3: weight transposes W (K x N fp32) -> WT (N x K bf16), 64x64 tiles.
// z=4: combined bias build. z=5: x fp32 -> bf16 convert.
// ---------------------------------------------------------------------------
__global__ __launch_bounds__(256) void transpose_all(
    const float* __restrict__ Wq, const float* __restrict__ Wkv,
    const float* __restrict__ Wg, const float* __restrict__ Wo,
    const float* __restrict__ bg, const float* __restrict__ x,
    short* __restrict__ WcT, short* __restrict__ WoT,
    float* __restrict__ bias, short* __restrict__ xb) {
  const int z = blockIdx.z;
  if (z == 4) {  // combined bias: [0,1024)=0, [1024,2048)=bg, [2048,2560)=0
    if (blockIdx.y == 0 && blockIdx.x < 10) {
      int i = blockIdx.x * 256 + threadIdx.x;
      if (i < 2560) bias[i] = (i >= 1024 && i < 2048) ? bg[i - 1024] : 0.f;
    }
    return;
  }
  if (z == 5) {  // x convert: 256 blocks x 256 threads x 16 float4
    int base = (blockIdx.y * 16 + blockIdx.x) * 256 + threadIdx.x;
#pragma unroll
    for (int it = 0; it < 16; ++it) {
      int i = base + it * 65536;
      float4 v = *(const float4*)&x[(size_t)i * 4];
      ushort4 o;
      o.x = f2b(v.x); o.y = f2b(v.y); o.z = f2b(v.z); o.w = f2b(v.w);
      *(ushort4*)&xb[(size_t)i * 4] = o;
    }
    return;
  }
  const float* W;
  short* WT;
  int N = 1024;
  const int K = 1024;
  if (z == 0) { W = Wq; WT = WcT; }
  else if (z == 1) { W = Wg; WT = WcT + 1048576; }
  else if (z == 2) {
    W = Wkv; WT = WcT + 2097152; N = 512;
    if (blockIdx.x >= 8) return;  // uniform early-out, before any sync
  } else { W = Wo; WT = WoT; }

  __shared__ short T[64 * 68];
  const int tid = threadIdx.x;
  const int n0 = blockIdx.x * 64, k0 = blockIdx.y * 64;
  {
    int i0 = tid >> 4, j4 = (tid & 15) * 4;
#pragma unroll
    for (int ii = 0; ii < 4; ++ii) {
      int i = i0 + 16 * ii;
      float4 w = *(const float4*)&W[(size_t)(k0 + i) * N + n0 + j4];
      ushort4 o;
      o.x = f2b(w.x); o.y = f2b(w.y); o.z = f2b(w.z); o.w = f2b(w.w);
      *(ushort4*)&T[i * 68 + j4] = o;
    }
  }
  __syncthreads();
  {
    int n = tid >> 2, k16 = (tid & 3) * 16;
    short tmp[16];
#pragma unroll
    for (int kk = 0; kk < 16; ++kk) tmp[kk] = T[(k16 + kk) * 68 + n];
    short* dst = WT + (size_t)(n0 + n) * K + k0 + k16;
#pragma unroll
    for (int s = 0; s < 16; s += 4) *(ushort4*)&dst[s] = *(const ushort4*)&tmp[s];
  }
}

// ---------------------------------------------------------------------------
// Fused projection GEMM (r19-proven 128x128) + XCD-chunk swizzle. Grid 20x32,
// 4 waves = 2x2 of (64m x 64n), acc[4][4]=64 AGPR, BK=32, dbuf gl_lds. (256,3).
// ---------------------------------------------------------------------------
__global__ __launch_bounds__(256, 3) void gemm_proj(
    const short* __restrict__ A, const short* __restrict__ WT,
    const float* __restrict__ bias, short* __restrict__ qc,
    short* __restrict__ gc, short* __restrict__ kc, short* __restrict__ vt) {
  __shared__ short As[2][128 * 32];
  __shared__ short Bs[2][128 * 32];
  const int tid = threadIdx.x;
  const int wave = tid >> 6, lane = tid & 63, l15 = lane & 15, quad = lane >> 4;
  const int bid0 = blockIdx.x + blockIdx.y * 20;
  const int swz = (bid0 & 7) * 80 + (bid0 >> 3);  // XCD chunk swizzle
  const int bx = swz % 20, by = swz / 20;
  const int m0 = by * 128, n0 = bx * 128;
  const int wm = (wave & 1) * 64, wn = (wave >> 1) * 64;
  const int arow = tid >> 2, ac = (tid & 3) * 8;
  const short* asrc = A + (size_t)(m0 + arow) * 1024 + ac;
  const short* bsrc = WT + (size_t)(n0 + arow) * 1024 + ac;

  gl_lds16(asrc, &As[0][wave * 512]);
  gl_lds16(asrc + 64 * 1024, &As[0][2048 + wave * 512]);
  gl_lds16(bsrc, &Bs[0][wave * 512]);
  gl_lds16(bsrc + 64 * 1024, &Bs[0][2048 + wave * 512]);

  f32x4 acc[4][4] = {};
  for (int k = 0; k < 32; ++k) {
    const int cur = k & 1;
    __syncthreads();  // stage(k) landed; iter k-1 LDS reads drained
    if (k < 31) {
      const short* ap = asrc + (k + 1) * 32;
      const short* bp = bsrc + (k + 1) * 32;
      gl_lds16(ap, &As[1 - cur][wave * 512]);
      gl_lds16(ap + 64 * 1024, &As[1 - cur][2048 + wave * 512]);
      gl_lds16(bp, &Bs[1 - cur][wave * 512]);
      gl_lds16(bp + 64 * 1024, &Bs[1 - cur][2048 + wave * 512]);
    }
    bf16x8 af[4], bfr[4];
#pragma unroll
    for (int i = 0; i < 4; ++i)
      af[i] = *(const bf16x8*)&As[cur][(wm + 16 * i + l15) * 32 + quad * 8];
#pragma unroll
    for (int j = 0; j < 4; ++j)
      bfr[j] = *(const bf16x8*)&Bs[cur][(wn + 16 * j + l15) * 32 + quad * 8];
#pragma unroll
    for (int i = 0; i < 4; ++i)
#pragma unroll
      for (int j = 0; j < 4; ++j) acc[i][j] = mfma16(af[i], bfr[j], acc[i][j]);
  }

  const int reg = (n0 + wn) >> 6;  // head-slot 0..39, WAVE-uniform
  if (reg < 16) {  // q: pre-scale by 0.125*log2e (softmax fold)
#pragma unroll
    for (int j = 0; j < 4; ++j) {
      int d = 16 * j + l15;
#pragma unroll
      for (int i = 0; i < 4; ++i)
#pragma unroll
        for (int r = 0; r < 4; ++r) {
          int row = m0 + wm + 16 * i + quad * 4 + r;
          int b = row >> 10, tok = row & 1023;
          ((unsigned short*)qc)[((size_t)((b * 16 + reg) * 1024 + tok)) * 64 + d] =
              f2b(acc[i][j][r] * 0.18033688f);
        }
    }
  } else if (reg < 32) {  // gate (+bias)
#pragma unroll
    for (int j = 0; j < 4; ++j) {
      int d = 16 * j + l15;
      float bv = bias[n0 + wn + d];
#pragma unroll
      for (int i = 0; i < 4; ++i)
#pragma unroll
        for (int r = 0; r < 4; ++r) {
          int row = m0 + wm + 16 * i + quad * 4 + r;
          int b = row >> 10, tok = row & 1023;
          ((unsigned short*)gc)[((size_t)((b * 16 + reg - 16) * 1024 + tok)) * 64 + d] =
              f2b(acc[i][j][r] + bv);
        }
    }
  } else if (reg < 36) {  // K fragment-packed
    int kvh = reg - 32;
#pragma unroll
    for (int j = 0; j < 4; ++j) {
      int d = 16 * j + l15;
      int dh = d >> 5, dq = (d >> 3) & 3, di = d & 7;
#pragma unroll
      for (int i = 0; i < 4; ++i)
#pragma unroll
        for (int r = 0; r < 4; ++r) {
          int row = m0 + wm + 16 * i + quad * 4 + r;
          int b = row >> 10, tok = row & 1023;
          int kt = tok >> 6, kh = (tok >> 5) & 1, k32 = tok & 31;
          int ksub = k32 >> 4, kl = k32 & 15;
          size_t koff = (size_t)(b * 4 + kvh) * 65536 +
                        (size_t)((kt * 2 + kh) * 2048 + (ksub * 2 + dh) * 512 +
                                 (dq * 16 + kl) * 8 + di);
          ((unsigned short*)kc)[koff] = f2b(acc[i][j][r]);
        }
    }
  } else {  // V fragment-packed (4 consecutive r -> one ushort4)
    int kvh = reg - 36;
#pragma unroll
    for (int j = 0; j < 4; ++j) {
      int dt = j;  // d = 16j + l15 -> dt = j, dl = l15
#pragma unroll
      for (int i = 0; i < 4; ++i) {
        int row0 = m0 + wm + 16 * i + quad * 4;
        int b = row0 >> 10, tok0 = row0 & 1023;
        int kt = tok0 >> 6, kh = (tok0 >> 5) & 1, isub = (tok0 >> 4) & 1;
        size_t voff = (size_t)(b * 4 + kvh) * 65536 +
                      (size_t)((kt * 2 + kh) * 2048 + (isub * 2 + (dt >> 1)) * 512 +
                               (quad * 16 + l15) * 8 + (dt & 1) * 4);
        ushort4 o;
        o.x = f2b(acc[i][j][0]);
        o.y = f2b(acc[i][j][1]);
        o.z = f2b(acc[i][j][2]);
        o.w = f2b(acc[i][j][3]);
        *(ushort4*)&((unsigned short*)vt)[voff] = o;
      }
    }
  }
}

// ---------------------------------------------------------------------------
// Output-projection GEMM (r21): 64x64 tile, BK=64 as two [64][32] sub-tiles,
// 1024 blocks = 4/CU, 16 barrier-steps at 8 MFMA each. + XCD swizzle.
// ---------------------------------------------------------------------------
__global__ __launch_bounds__(256, 4) void gemm_out(
    const short* __restrict__ A, const short* __restrict__ WT,
    float* __restrict__ Cout) {
  __shared__ short As[2][2][64 * 32];
  __shared__ short Bs[2][2][64 * 32];
  const int tid = threadIdx.x;
  const int wave = tid >> 6, lane = tid & 63, l15 = lane & 15, quad = lane >> 4;
  const int bid0 = blockIdx.x + blockIdx.y * 16;
  const int swz = (bid0 & 7) * 128 + (bid0 >> 3);  // nwg=1024, cpx=128
  const int m0 = (swz >> 4) * 64, n0 = (swz & 15) * 64;
  const int wm = (wave & 1) * 32, wn = (wave >> 1) * 32;
  const int arow = tid >> 2, ac = (tid & 3) * 8;
  const short* asrc = A + (size_t)(m0 + arow) * 1024 + ac;
  const short* bsrc = WT + (size_t)(n0 + arow) * 1024 + ac;

  // stage K-step 0: cols 0..63 as two 32-col subs (each the proven layout)
  gl_lds16(asrc, &As[0][0][wave * 512]);
  gl_lds16(asrc + 32, &As[0][1][wave * 512]);
  gl_lds16(bsrc, &Bs[0][0][wave * 512]);
  gl_lds16(bsrc + 32, &Bs[0][1][wave * 512]);

  f32x4 acc[2][2] = {};
  for (int k = 0; k < 16; ++k) {
    const int cur = k & 1;
    __syncthreads();  // stage(k) landed; iter k-1 LDS reads drained
    if (k < 15) {
      const short* ap = asrc + (k + 1) * 64;
      const short* bp = bsrc + (k + 1) * 64;
      gl_lds16(ap, &As[1 - cur][0][wave * 512]);
      gl_lds16(ap + 32, &As[1 - cur][1][wave * 512]);
      gl_lds16(bp, &Bs[1 - cur][0][wave * 512]);
      gl_lds16(bp + 32, &Bs[1 - cur][1][wave * 512]);
    }
#pragma unroll
    for (int s = 0; s < 2; ++s) {
      bf16x8 af[2], bfr[2];
#pragma unroll
      for (int i = 0; i < 2; ++i)
        af[i] = *(const bf16x8*)&As[cur][s][(wm + 16 * i + l15) * 32 + quad * 8];
#pragma unroll
      for (int j = 0; j < 2; ++j)
        bfr[j] = *(const bf16x8*)&Bs[cur][s][(wn + 16 * j + l15) * 32 + quad * 8];
#pragma unroll
      for (int i = 0; i < 2; ++i)
#pragma unroll
        for (int j = 0; j < 2; ++j) acc[i][j] = mfma16(af[i], bfr[j], acc[i][j]);
    }
  }
#pragma unroll
  for (int j = 0; j < 2; ++j) {
    int col = n0 + wn + 16 * j + l15;
#pragma unroll
    for (int i = 0; i < 2; ++i) {
#pragma unroll
      for (int r = 0; r < 4; ++r) {
        int row = m0 + wm + 16 * i + quad * 4 + r;
        Cout[(size_t)row * 1024 + col] = acc[i][j][r];
      }
    }
  }
}

// ---------------------------------------------------------------------------
// MFMA flash attention + gate, round 22: 128 q-rows per block (was 64).
// r19-r21 plateau analysis: attn ~36us vs ~13us floor with both r17
// (reg-direct) and r20 (LDS-staged) variants identical -> cost is per-kt
// stage+barrier overhead paid once per 64 q-rows. Doubling q-rows per block
// halves that overhead per unit work AND halves K/V L2 traffic (268->134MB).
// Grid 512 = 8qt x 64bh, all co-resident at 2 blocks/CU, (256,2): cap 256
// unified; oacc 64 AGPR + qf 32 + frags 32 + temps ~30 = ~160, no spill.
// Wave w = (qh=w>>1 owns 64 q-rows, kh=w&1 owns 32 keys/kt). Same proven
// packed K/V layout, LDS staging, in-register P->PV.
// ---------------------------------------------------------------------------
__global__ __launch_bounds__(256, 2) void attn_mfma16(
    const short* __restrict__ qc, const short* __restrict__ gc,
    const short* __restrict__ kc, const short* __restrict__ vt,
    unsigned short* __restrict__ gated) {
  __shared__ short KV[2][8192];   // [buf][ K 4096 sh | V 4096 sh ] = 32 KB
  __shared__ float Obuf[2 * 64 * 65];  // qh0 | qh1 partial O^T [d][q&63]
  __shared__ float Lpart[4 * 64];
  __shared__ float Lq[128];
  const int tid = threadIdx.x;
  const int w = tid >> 6, lane = tid & 63, l15 = lane & 15, quad = lane >> 4;
  const int qh = w >> 1, kh = w & 1;
  const int bid0 = blockIdx.x + blockIdx.y * 8;
  const int swz = (bid0 & 7) * 64 + (bid0 >> 3);  // nwg=512, cpx=64
  const int qt = swz & 7, bh = swz >> 3;
  const int b = bh >> 4, h = bh & 15, kvh = h >> 2;

  // Q B-frags: col q = qt*128 + qh*64 + 16jq + l15, k = d = quad*8+i (+32)
  bf16x8 qf[4][2];
#pragma unroll
  for (int jq = 0; jq < 4; ++jq) {
    const short* qp = qc + ((size_t)((b * 16 + h) * 1024) + qt * 128 + qh * 64 +
                            16 * jq + l15) * 64 + quad * 8;
    qf[jq][0] = *(const bf16x8*)qp;
    qf[jq][1] = *(const bf16x8*)(qp + 32);
  }

  const short* kbase = kc + (size_t)(b * 4 + kvh) * 65536;  // + kt*4096
  const short* vbase = vt + (size_t)(b * 4 + kvh) * 65536;
  const int wdst = w * 512;  // wave-uniform LDS dest (64 lanes x 8 sh)

#define STAGE(CUR, KT)                                                         \
  {                                                                            \
    const short* ks = kbase + (size_t)(KT) * 4096;                             \
    const short* vs = vbase + (size_t)(KT) * 4096;                             \
    gl_lds16(ks + tid * 8, &KV[CUR][wdst]);                                    \
    gl_lds16(ks + 2048 + tid * 8, &KV[CUR][2048 + wdst]);                      \
    gl_lds16(vs + tid * 8, &KV[CUR][4096 + wdst]);                             \
    gl_lds16(vs + 2048 + tid * 8, &KV[CUR][6144 + wdst]);                      \
  }

  f32x4 oacc[4][4] = {};  // [jq][dt]: d = 16dt+4quad+r, q = qh*64+16jq+l15
  float ls[4] = {0.f, 0.f, 0.f, 0.f};

#define EXPPV8(ST, JQ, WA, WB)                                                 \
  {                                                                            \
    float p0 = exp2f((ST)[0]), p1 = exp2f((ST)[1]);                            \
    float p2 = exp2f((ST)[2]), p3 = exp2f((ST)[3]);                            \
    ls[JQ] += (p0 + p1) + (p2 + p3);                                           \
    bf16x4 pbf;                                                                \
    pbf[0] = (short)f2b(p0);                                                   \
    pbf[1] = (short)f2b(p1);                                                   \
    pbf[2] = (short)f2b(p2);                                                   \
    pbf[3] = (short)f2b(p3);                                                   \
    oacc[JQ][0] = mfma16k16(vlo(WA), pbf, oacc[JQ][0]);                        \
    oacc[JQ][1] = mfma16k16(vhi(WA), pbf, oacc[JQ][1]);                        \
    oacc[JQ][2] = mfma16k16(vlo(WB), pbf, oacc[JQ][2]);                        \
    oacc[JQ][3] = mfma16k16(vhi(WB), pbf, oacc[JQ][3]);                        \
  }

  STAGE(0, 0);
  for (int kt = 0; kt < 16; ++kt) {
    const int cur = kt & 1;
    __syncthreads();  // stage(kt) landed (barrier drains vmcnt)
    if (kt < 15) STAGE(cur ^ 1, kt + 1);
    const short* kl = &KV[cur][kh * 2048 + lane * 8];
    const short* vl = &KV[cur][4096 + kh * 2048 + lane * 8];
    bf16x8 kA0 = *(const bf16x8*)(kl);
    bf16x8 kA1 = *(const bf16x8*)(kl + 512);
    bf16x8 kA2 = *(const bf16x8*)(kl + 1024);
    bf16x8 kA3 = *(const bf16x8*)(kl + 1536);
    bf16x8 w0 = *(const bf16x8*)(vl);
    bf16x8 w1 = *(const bf16x8*)(vl + 512);
    bf16x8 w2 = *(const bf16x8*)(vl + 1024);
    bf16x8 w3 = *(const bf16x8*)(vl + 1536);
    // ---- keysub0: S then exp+PV, all 4 jq
#pragma unroll
    for (int jq = 0; jq < 4; ++jq) {
      f32x4 st = mfma16(kA0, qf[jq][0], (f32x4){0.f, 0.f, 0.f, 0.f});
      st = mfma16(kA1, qf[jq][1], st);
      EXPPV8(st, jq, w0, w1);
    }
    // ---- keysub1
#pragma unroll
    for (int jq = 0; jq < 4; ++jq) {
      f32x4 st = mfma16(kA2, qf[jq][0], (f32x4){0.f, 0.f, 0.f, 0.f});
      st = mfma16(kA3, qf[jq][1], st);
      EXPPV8(st, jq, w2, w3);
    }
  }
#undef EXPPV8
#undef STAGE

  // l reduction: quad-reduce in-wave (sum over this wave's 512 keys per q)
#pragma unroll
  for (int jq = 0; jq < 4; ++jq) {
    ls[jq] += __shfl_xor(ls[jq], 16);
    ls[jq] += __shfl_xor(ls[jq], 32);
  }
  if (quad == 0) {
#pragma unroll
    for (int jq = 0; jq < 4; ++jq) Lpart[w * 64 + 16 * jq + l15] = ls[jq];
  }

  // cross-wave O reduction: kh=0 waves write their qh buffer; kh=1 waves add.
  float* Ob = Obuf + qh * (64 * 65);
  if (kh == 0) {
#pragma unroll
    for (int jq = 0; jq < 4; ++jq)
#pragma unroll
      for (int dt = 0; dt < 4; ++dt)
#pragma unroll
        for (int r = 0; r < 4; ++r)
          Ob[(16 * dt + 4 * quad + r) * 65 + 16 * jq + l15] = oacc[jq][dt][r];
  }
  __syncthreads();
  if (kh == 1) {
#pragma unroll
    for (int jq = 0; jq < 4; ++jq)
#pragma unroll
      for (int dt = 0; dt < 4; ++dt)
#pragma unroll
        for (int r = 0; r < 4; ++r)
          Ob[(16 * dt + 4 * quad + r) * 65 + 16 * jq + l15] += oacc[jq][dt][r];
  }
  if (tid < 128) {
    int ql = tid & 63, qh2 = tid >> 6;
    Lq[tid] = Lpart[qh2 * 128 + ql] + Lpart[qh2 * 128 + 64 + ql];
  }
  __syncthreads();

  // epilogue: O rows q = 16jq+4quad+r (jq 0..7 -> 128 rows), cols d = 16w+l15
  const int d = 16 * w + l15;
#pragma unroll
  for (int jq = 0; jq < 8; ++jq) {
    const float* Osrc = Obuf + (jq < 4 ? 0 : 64 * 65);
#pragma unroll
    for (int r = 0; r < 4; ++r) {
      int qloc = 16 * jq + 4 * quad + r;
      float ov = Osrc[d * 65 + (qloc & 63)];
      float lv = Lq[qloc];
      float gv = b2f(((const unsigned short*)gc)[
          ((size_t)((b * 16 + h) * 1024) + qt * 128 + qloc) * 64 + d]);
      size_t row = (size_t)(b * NN + qt * 128 + qloc);
      gated[row * 1024 + h * 64 + d] = f2b(ov / lv * gv);
    }
  }
}

// ---------------------------------------------------------------------------
extern "C" void kernel_launch(void* const* d_in, const int* in_sizes, int n_in,
                              void* d_out, int out_size, void* d_ws,
                              size_t ws_size, hipStream_t stream) {
  const float* x = (const float*)d_in[0];
  const float* Wq = (const float*)d_in[1];
  const float* Wkv = (const float*)d_in[2];
  const float* Wg = (const float*)d_in[3];
  const float* bg = (const float*)d_in[4];
  const float* Wo = (const float*)d_in[5];
  float* out = (float*)d_out;

  // ws layout (short elems): ~36.6 MB total
  short* ws = (short*)d_ws;
  short* xb = ws;                     // 4.19M (x bf16; later aliased as gated)
  short* WcT = xb + 4194304;          // 2.62M (W^T combined: q|g|kv rows)
  short* WoT = WcT + 2621440;         // 1.05M
  short* qc = WoT + 1048576;          // 4.19M  q[b,h,tok,d]
  short* gc = qc + 4194304;           // 4.19M  gate[b,h,tok,d]
  short* kc = gc + 4194304;           // 1.05M  K fragment-packed
  short* vtw = kc + 1048576;          // 1.05M  V fragment-packed
  float* bias_f32 = (float*)(vtw + 1048576);  // 2560 f32

  dim3 blk(256);
  // weight transposes + bias + x-convert, one dispatch
  transpose_all<<<dim3(16, 16, 6), blk, 0, stream>>>(Wq, Wkv, Wg, Wo, bg, x,
                                                     WcT, WoT, bias_f32, xb);
  // fused q|gate|kv projection (outputs diverted to packed layouts)
  gemm_proj<<<dim3(20, 32), blk, 0, stream>>>(xb, WcT, bias_f32, qc, gc, kc, vtw);
  // attention + gate -> gated (aliases xb; xb no longer needed)
  attn_mfma16<<<dim3(8, 64), blk, 0, stream>>>(qc, gc, kc, vtw, (unsigned short*)xb);
  // output projection
  gemm_out<<<dim3(16, 64), blk, 0, stream>>>(xb, WoT, out);
}

// Round 14
// 169.791 us; speedup vs baseline: 1.0095x; 1.0095x over previous
//
#include <hip/hip_runtime.h>
#include <hip/hip_bf16.h>
#include <stdint.h>

#define BB 4
#define NN 1024
#define DD 1024
#define HH 16
#define HDIM 64
#define KVHH 4
#define MM (BB * NN)  // 4096 token rows

typedef __hip_bfloat16 bf16;
typedef __attribute__((ext_vector_type(8))) short bf16x8;  // 8 bf16 = 4 VGPR
typedef __attribute__((ext_vector_type(4))) short bf16x4;  // 4 bf16 = 2 VGPR
typedef __attribute__((ext_vector_type(4))) float f32x4;

__device__ __forceinline__ float b2f(unsigned short u) {
  return __uint_as_float(((unsigned)u) << 16);
}
__device__ __forceinline__ unsigned short f2b(float x) {
  bf16 h = __float2bfloat16(x);
  unsigned short u;
  __builtin_memcpy(&u, &h, 2);
  return u;
}
__device__ __forceinline__ f32x4 mfma16(bf16x8 a, bf16x8 b, f32x4 c) {
  return __builtin_amdgcn_mfma_f32_16x16x32_bf16(a, b, c, 0, 0, 0);
}
// K=16 MFMA: B-fragment layout (col=l15, k=quad*4+i) matches the K=32 MFMA's
// C layout (col=l15, row=quad*4+r) -> S output feeds PV directly, in-register.
// (Correctness HW-verified r12-r22: absmax identical across all rounds.)
__device__ __forceinline__ f32x4 mfma16k16(bf16x4 a, bf16x4 b, f32x4 c) {
#if __has_builtin(__builtin_amdgcn_mfma_f32_16x16x16bf16_1k)
  return __builtin_amdgcn_mfma_f32_16x16x16bf16_1k(a, b, c, 0, 0, 0);
#else
  asm("s_nop 1\n\tv_mfma_f32_16x16x16_bf16 %0, %1, %2, %0"
      : "+v"(c)
      : "v"(a), "v"(b));
  return c;
#endif
}
__device__ __forceinline__ bf16x4 vlo(bf16x8 v) {
  return __builtin_shufflevector(v, v, 0, 1, 2, 3);
}
__device__ __forceinline__ bf16x4 vhi(bf16x8 v) {
  return __builtin_shufflevector(v, v, 4, 5, 6, 7);
}
__device__ __forceinline__ void gl_lds16(const short* g, short* l) {
  __builtin_amdgcn_global_load_lds(
      (const __attribute__((address_space(1))) unsigned*)g,
      (__attribute__((address_space(3))) unsigned*)l, 16, 0, 0);
}

// ---------------------------------------------------------------------------
// z=0..3: weight transposes W (K x N fp32) -> WT (N x K bf16), 64x64 tiles.
// z=4: combined bias build. z=5: x fp32 -> bf16 convert.
// ---------------------------------------------------------------------------
__global__ __launch_bounds__(256) void transpose_all(
    const float* __restrict__ Wq, const float* __restrict__ Wkv,
    const float* __restrict__ Wg, const float* __restrict__ Wo,
    const float* __restrict__ bg, const float* __restrict__ x,
    short* __restrict__ WcT, short* __restrict__ WoT,
    float* __restrict__ bias, short* __restrict__ xb) {
  const int z = blockIdx.z;
  if (z == 4) {  // combined bias: [0,1024)=0, [1024,2048)=bg, [2048,2560)=0
    if (blockIdx.y == 0 && blockIdx.x < 10) {
      int i = blockIdx.x * 256 + threadIdx.x;
      if (i < 2560) bias[i] = (i >= 1024 && i < 2048) ? bg[i - 1024] : 0.f;
    }
    return;
  }
  if (z == 5) {  // x convert: 256 blocks x 256 threads x 16 float4
    int base = (blockIdx.y * 16 + blockIdx.x) * 256 + threadIdx.x;
#pragma unroll
    for (int it = 0; it < 16; ++it) {
      int i = base + it * 65536;
      float4 v = *(const float4*)&x[(size_t)i * 4];
      ushort4 o;
      o.x = f2b(v.x); o.y = f2b(v.y); o.z = f2b(v.z); o.w = f2b(v.w);
      *(ushort4*)&xb[(size_t)i * 4] = o;
    }
    return;
  }
  const float* W;
  short* WT;
  int N = 1024;
  const int K = 1024;
  if (z == 0) { W = Wq; WT = WcT; }
  else if (z == 1) { W = Wg; WT = WcT + 1048576; }
  else if (z == 2) {
    W = Wkv; WT = WcT + 2097152; N = 512;
    if (blockIdx.x >= 8) return;  // uniform early-out, before any sync
  } else { W = Wo; WT = WoT; }

  __shared__ short T[64 * 68];
  const int tid = threadIdx.x;
  const int n0 = blockIdx.x * 64, k0 = blockIdx.y * 64;
  {
    int i0 = tid >> 4, j4 = (tid & 15) * 4;
#pragma unroll
    for (int ii = 0; ii < 4; ++ii) {
      int i = i0 + 16 * ii;
      float4 w = *(const float4*)&W[(size_t)(k0 + i) * N + n0 + j4];
      ushort4 o;
      o.x = f2b(w.x); o.y = f2b(w.y); o.z = f2b(w.z); o.w = f2b(w.w);
      *(ushort4*)&T[i * 68 + j4] = o;
    }
  }
  __syncthreads();
  {
    int n = tid >> 2, k16 = (tid & 3) * 16;
    short tmp[16];
#pragma unroll
    for (int kk = 0; kk < 16; ++kk) tmp[kk] = T[(k16 + kk) * 68 + n];
    short* dst = WT + (size_t)(n0 + n) * K + k0 + k16;
#pragma unroll
    for (int s = 0; s < 16; s += 4) *(ushort4*)&dst[s] = *(const ushort4*)&tmp[s];
  }
}

// ---------------------------------------------------------------------------
// Fused projection GEMM, round 24: 128x128 tile + TRIPLE-buffered LDS with
// counted vmcnt (T4). The old 2-buffer loop drained vmcnt(0) at every
// __syncthreads (m97's structural ~20% stall). Now: stage(k+2) issued each
// step; s_waitcnt vmcnt(4) (stage(k) landed, stage(k+1) still flying) BEFORE
// a raw s_barrier. Hazard proof: each wave's compiler-emitted lgkmcnt before
// its MFMAs completes its buf-reads before it reaches the next barrier, so a
// post-barrier STAGE into that buffer is race-free; vmcnt(4)+barrier orders
// all waves' stage(k) before any ds_read of buf(k). Tail peeled w/ vmcnt(0).
// LDS 48KB x 3 blocks = 144KB. (256,3). + XCD swizzle.
// ---------------------------------------------------------------------------
__global__ __launch_bounds__(256, 3) void gemm_proj(
    const short* __restrict__ A, const short* __restrict__ WT,
    const float* __restrict__ bias, short* __restrict__ qc,
    short* __restrict__ gc, short* __restrict__ kc, short* __restrict__ vt) {
  __shared__ short As[3][128 * 32];
  __shared__ short Bs[3][128 * 32];
  const int tid = threadIdx.x;
  const int wave = tid >> 6, lane = tid & 63, l15 = lane & 15, quad = lane >> 4;
  const int bid0 = blockIdx.x + blockIdx.y * 20;
  const int swz = (bid0 & 7) * 80 + (bid0 >> 3);  // XCD chunk swizzle
  const int bx = swz % 20, by = swz / 20;
  const int m0 = by * 128, n0 = bx * 128;
  const int wm = (wave & 1) * 64, wn = (wave >> 1) * 64;
  const int arow = tid >> 2, ac = (tid & 3) * 8;
  const short* asrc = A + (size_t)(m0 + arow) * 1024 + ac;
  const short* bsrc = WT + (size_t)(n0 + arow) * 1024 + ac;

#define PSTAGE(BUF, K)                                                         \
  {                                                                            \
    const short* ap = asrc + (K)*32;                                           \
    const short* bp = bsrc + (K)*32;                                           \
    gl_lds16(ap, &As[BUF][wave * 512]);                                        \
    gl_lds16(ap + 64 * 1024, &As[BUF][2048 + wave * 512]);                     \
    gl_lds16(bp, &Bs[BUF][wave * 512]);                                        \
    gl_lds16(bp + 64 * 1024, &Bs[BUF][2048 + wave * 512]);                     \
  }

  PSTAGE(0, 0);
  PSTAGE(1, 1);

  f32x4 acc[4][4] = {};
  for (int k = 0; k < 32; ++k) {
    const int cur = k % 3;
    if (k < 31)
      asm volatile("s_waitcnt vmcnt(4)" ::: "memory");  // stage(k) landed
    else
      asm volatile("s_waitcnt vmcnt(0)" ::: "memory");  // last: drain all
    __builtin_amdgcn_s_barrier();  // all waves' stage(k) visible
    __builtin_amdgcn_sched_barrier(0);
    if (k < 30) PSTAGE((k + 2) % 3, k + 2);  // overwrites buf read at k-1 (safe)
    bf16x8 af[4], bfr[4];
#pragma unroll
    for (int i = 0; i < 4; ++i)
      af[i] = *(const bf16x8*)&As[cur][(wm + 16 * i + l15) * 32 + quad * 8];
#pragma unroll
    for (int j = 0; j < 4; ++j)
      bfr[j] = *(const bf16x8*)&Bs[cur][(wn + 16 * j + l15) * 32 + quad * 8];
#pragma unroll
    for (int i = 0; i < 4; ++i)
#pragma unroll
      for (int j = 0; j < 4; ++j) acc[i][j] = mfma16(af[i], bfr[j], acc[i][j]);
  }
#undef PSTAGE

  const int reg = (n0 + wn) >> 6;  // head-slot 0..39, WAVE-uniform
  if (reg < 16) {  // q: pre-scale by 0.125*log2e (softmax fold)
#pragma unroll
    for (int j = 0; j < 4; ++j) {
      int d = 16 * j + l15;
#pragma unroll
      for (int i = 0; i < 4; ++i)
#pragma unroll
        for (int r = 0; r < 4; ++r) {
          int row = m0 + wm + 16 * i + quad * 4 + r;
          int b = row >> 10, tok = row & 1023;
          ((unsigned short*)qc)[((size_t)((b * 16 + reg) * 1024 + tok)) * 64 + d] =
              f2b(acc[i][j][r] * 0.18033688f);
        }
    }
  } else if (reg < 32) {  // gate (+bias)
#pragma unroll
    for (int j = 0; j < 4; ++j) {
      int d = 16 * j + l15;
      float bv = bias[n0 + wn + d];
#pragma unroll
      for (int i = 0; i < 4; ++i)
#pragma unroll
        for (int r = 0; r < 4; ++r) {
          int row = m0 + wm + 16 * i + quad * 4 + r;
          int b = row >> 10, tok = row & 1023;
          ((unsigned short*)gc)[((size_t)((b * 16 + reg - 16) * 1024 + tok)) * 64 + d] =
              f2b(acc[i][j][r] + bv);
        }
    }
  } else if (reg < 36) {  // K fragment-packed
    int kvh = reg - 32;
#pragma unroll
    for (int j = 0; j < 4; ++j) {
      int d = 16 * j + l15;
      int dh = d >> 5, dq = (d >> 3) & 3, di = d & 7;
#pragma unroll
      for (int i = 0; i < 4; ++i)
#pragma unroll
        for (int r = 0; r < 4; ++r) {
          int row = m0 + wm + 16 * i + quad * 4 + r;
          int b = row >> 10, tok = row & 1023;
          int kt = tok >> 6, kh = (tok >> 5) & 1, k32 = tok & 31;
          int ksub = k32 >> 4, kl = k32 & 15;
          size_t koff = (size_t)(b * 4 + kvh) * 65536 +
                        (size_t)((kt * 2 + kh) * 2048 + (ksub * 2 + dh) * 512 +
                                 (dq * 16 + kl) * 8 + di);
          ((unsigned short*)kc)[koff] = f2b(acc[i][j][r]);
        }
    }
  } else {  // V fragment-packed (4 consecutive r -> one ushort4)
    int kvh = reg - 36;
#pragma unroll
    for (int j = 0; j < 4; ++j) {
      int dt = j;  // d = 16j + l15 -> dt = j, dl = l15
#pragma unroll
      for (int i = 0; i < 4; ++i) {
        int row0 = m0 + wm + 16 * i + quad * 4;
        int b = row0 >> 10, tok0 = row0 & 1023;
        int kt = tok0 >> 6, kh = (tok0 >> 5) & 1, isub = (tok0 >> 4) & 1;
        size_t voff = (size_t)(b * 4 + kvh) * 65536 +
                      (size_t)((kt * 2 + kh) * 2048 + (isub * 2 + (dt >> 1)) * 512 +
                               (quad * 16 + l15) * 8 + (dt & 1) * 4);
        ushort4 o;
        o.x = f2b(acc[i][j][0]);
        o.y = f2b(acc[i][j][1]);
        o.z = f2b(acc[i][j][2]);
        o.w = f2b(acc[i][j][3]);
        *(ushort4*)&((unsigned short*)vt)[voff] = o;
      }
    }
  }
}

// ---------------------------------------------------------------------------
// Output-projection GEMM (r21): 64x64 tile, BK=64 as two [64][32] sub-tiles,
// 1024 blocks = 4/CU, 16 barrier-steps at 8 MFMA each. + XCD swizzle.
// ---------------------------------------------------------------------------
__global__ __launch_bounds__(256, 4) void gemm_out(
    const short* __restrict__ A, const short* __restrict__ WT,
    float* __restrict__ Cout) {
  __shared__ short As[2][2][64 * 32];
  __shared__ short Bs[2][2][64 * 32];
  const int tid = threadIdx.x;
  const int wave = tid >> 6, lane = tid & 63, l15 = lane & 15, quad = lane >> 4;
  const int bid0 = blockIdx.x + blockIdx.y * 16;
  const int swz = (bid0 & 7) * 128 + (bid0 >> 3);  // nwg=1024, cpx=128
  const int m0 = (swz >> 4) * 64, n0 = (swz & 15) * 64;
  const int wm = (wave & 1) * 32, wn = (wave >> 1) * 32;
  const int arow = tid >> 2, ac = (tid & 3) * 8;
  const short* asrc = A + (size_t)(m0 + arow) * 1024 + ac;
  const short* bsrc = WT + (size_t)(n0 + arow) * 1024 + ac;

  // stage K-step 0: cols 0..63 as two 32-col subs (each the proven layout)
  gl_lds16(asrc, &As[0][0][wave * 512]);
  gl_lds16(asrc + 32, &As[0][1][wave * 512]);
  gl_lds16(bsrc, &Bs[0][0][wave * 512]);
  gl_lds16(bsrc + 32, &Bs[0][1][wave * 512]);

  f32x4 acc[2][2] = {};
  for (int k = 0; k < 16; ++k) {
    const int cur = k & 1;
    __syncthreads();  // stage(k) landed; iter k-1 LDS reads drained
    if (k < 15) {
      const short* ap = asrc + (k + 1) * 64;
      const short* bp = bsrc + (k + 1) * 64;
      gl_lds16(ap, &As[1 - cur][0][wave * 512]);
      gl_lds16(ap + 32, &As[1 - cur][1][wave * 512]);
      gl_lds16(bp, &Bs[1 - cur][0][wave * 512]);
      gl_lds16(bp + 32, &Bs[1 - cur][1][wave * 512]);
    }
#pragma unroll
    for (int s = 0; s < 2; ++s) {
      bf16x8 af[2], bfr[2];
#pragma unroll
      for (int i = 0; i < 2; ++i)
        af[i] = *(const bf16x8*)&As[cur][s][(wm + 16 * i + l15) * 32 + quad * 8];
#pragma unroll
      for (int j = 0; j < 2; ++j)
        bfr[j] = *(const bf16x8*)&Bs[cur][s][(wn + 16 * j + l15) * 32 + quad * 8];
#pragma unroll
      for (int i = 0; i < 2; ++i)
#pragma unroll
        for (int j = 0; j < 2; ++j) acc[i][j] = mfma16(af[i], bfr[j], acc[i][j]);
    }
  }
#pragma unroll
  for (int j = 0; j < 2; ++j) {
    int col = n0 + wn + 16 * j + l15;
#pragma unroll
    for (int i = 0; i < 2; ++i) {
#pragma unroll
      for (int r = 0; r < 4; ++r) {
        int row = m0 + wm + 16 * i + quad * 4 + r;
        Cout[(size_t)row * 1024 + col] = acc[i][j][r];
      }
    }
  }
}

// ---------------------------------------------------------------------------
// MFMA flash attention + gate (r20 REVERT — r22's 128-row block regressed:
// occupancy 16%, softmax VALU exposed). LDS-shared K/V staging, 2x2 wave
// split, in-register P->PV, OA/OB alias dead KV LDS. 4 blocks/CU.
// ---------------------------------------------------------------------------
__global__ __launch_bounds__(256, 4) void attn_mfma15(
    const short* __restrict__ qc, const short* __restrict__ gc,
    const short* __restrict__ kc, const short* __restrict__ vt,
    unsigned short* __restrict__ gated) {
  __shared__ short KV[2][8192];  // [buf][ K 4096 sh | V 4096 sh ] = 32 KB
  __shared__ float Lpart[4 * 32];
  __shared__ float Lq[64];
  float* OA = (float*)&KV[0][0];  // aliased AFTER main loop (barrier-fenced)
  float* OB = OA + 64 * 33;
  const int tid = threadIdx.x;
  const int w = tid >> 6, lane = tid & 63, l15 = lane & 15, quad = lane >> 4;
  const int qh = w >> 1, kh = w & 1;
  const int bid0 = blockIdx.x + blockIdx.y * 16;
  const int swz = (bid0 & 7) * 128 + (bid0 >> 3);  // nwg=1024, cpx=128
  const int qt = swz & 15, bh = swz >> 4;
  const int b = bh >> 4, h = bh & 15, kvh = h >> 2;

  // Q B-frags: col q = qt*64 + qh*32 + 16jq + l15, k = d = quad*8+i (+32)
  bf16x8 qf[2][2];
#pragma unroll
  for (int jq = 0; jq < 2; ++jq) {
    const short* qp = qc + ((size_t)((b * 16 + h) * 1024) + qt * 64 + qh * 32 +
                            16 * jq + l15) * 64 + quad * 8;
    qf[jq][0] = *(const bf16x8*)qp;
    qf[jq][1] = *(const bf16x8*)(qp + 32);
  }

  const short* kbase = kc + (size_t)(b * 4 + kvh) * 65536;  // + kt*4096
  const short* vbase = vt + (size_t)(b * 4 + kvh) * 65536;
  const int wdst = w * 512;  // wave-uniform LDS dest (64 lanes x 8 sh)

#define STAGE(CUR, KT)                                                         \
  {                                                                            \
    const short* ks = kbase + (size_t)(KT) * 4096;                             \
    const short* vs = vbase + (size_t)(KT) * 4096;                             \
    gl_lds16(ks + tid * 8, &KV[CUR][wdst]);                                    \
    gl_lds16(ks + 2048 + tid * 8, &KV[CUR][2048 + wdst]);                      \
    gl_lds16(vs + tid * 8, &KV[CUR][4096 + wdst]);                             \
    gl_lds16(vs + 2048 + tid * 8, &KV[CUR][6144 + wdst]);                      \
  }

  f32x4 oacc[2][4] = {};  // [jq][dt]: d = 16dt+4quad+r, q = qh*32+16jq+l15
  float ls[2] = {0.f, 0.f};

#define EXPPV8(ST, JQ, WA, WB)                                                 \
  {                                                                            \
    float p0 = exp2f((ST)[0]), p1 = exp2f((ST)[1]);                            \
    float p2 = exp2f((ST)[2]), p3 = exp2f((ST)[3]);                            \
    ls[JQ] += (p0 + p1) + (p2 + p3);                                           \
    bf16x4 pbf;                                                                \
    pbf[0] = (short)f2b(p0);                                                   \
    pbf[1] = (short)f2b(p1);                                                   \
    pbf[2] = (short)f2b(p2);                                                   \
    pbf[3] = (short)f2b(p3);                                                   \
    oacc[JQ][0] = mfma16k16(vlo(WA), pbf, oacc[JQ][0]);                        \
    oacc[JQ][1] = mfma16k16(vhi(WA), pbf, oacc[JQ][1]);                        \
    oacc[JQ][2] = mfma16k16(vlo(WB), pbf, oacc[JQ][2]);                        \
    oacc[JQ][3] = mfma16k16(vhi(WB), pbf, oacc[JQ][3]);                        \
  }

  STAGE(0, 0);
  for (int kt = 0; kt < 16; ++kt) {
    const int cur = kt & 1;
    __syncthreads();  // stage(kt) landed (barrier drains vmcnt)
    if (kt < 15) STAGE(cur ^ 1, kt + 1);
    const short* kl = &KV[cur][kh * 2048 + lane * 8];
    const short* vl = &KV[cur][4096 + kh * 2048 + lane * 8];
    bf16x8 kA0 = *(const bf16x8*)(kl);
    bf16x8 kA1 = *(const bf16x8*)(kl + 512);
    bf16x8 kA2 = *(const bf16x8*)(kl + 1024);
    bf16x8 kA3 = *(const bf16x8*)(kl + 1536);
    bf16x8 w0 = *(const bf16x8*)(vl);
    bf16x8 w1 = *(const bf16x8*)(vl + 512);
    bf16x8 w2 = *(const bf16x8*)(vl + 1024);
    bf16x8 w3 = *(const bf16x8*)(vl + 1536);
    // ---- S keysub0, both jq
    f32x4 s00 = mfma16(kA0, qf[0][0], (f32x4){0.f, 0.f, 0.f, 0.f});
    s00 = mfma16(kA1, qf[0][1], s00);
    f32x4 s10 = mfma16(kA0, qf[1][0], (f32x4){0.f, 0.f, 0.f, 0.f});
    s10 = mfma16(kA1, qf[1][1], s10);
    EXPPV8(s00, 0, w0, w1);
    EXPPV8(s10, 1, w0, w1);
    // ---- S keysub1
    f32x4 s01 = mfma16(kA2, qf[0][0], (f32x4){0.f, 0.f, 0.f, 0.f});
    s01 = mfma16(kA3, qf[0][1], s01);
    f32x4 s11 = mfma16(kA2, qf[1][0], (f32x4){0.f, 0.f, 0.f, 0.f});
    s11 = mfma16(kA3, qf[1][1], s11);
    EXPPV8(s01, 0, w2, w3);
    EXPPV8(s11, 1, w2, w3);
  }
#undef EXPPV8
#undef STAGE

  // l reduction: quad-reduce in-wave (sum over this wave's 512 keys per q)
#pragma unroll
  for (int jq = 0; jq < 2; ++jq) {
    ls[jq] += __shfl_xor(ls[jq], 16);
    ls[jq] += __shfl_xor(ls[jq], 32);
  }
  __syncthreads();  // all KV ds_reads done before OA/OB alias the same LDS
  if (quad == 0) {
#pragma unroll
    for (int jq = 0; jq < 2; ++jq) Lpart[w * 32 + 16 * jq + l15] = ls[jq];
  }
  // cross-wave O reduction: kh=0 waves write their qh buffer; kh=1 waves add.
  float* Ob = qh ? OB : OA;
  if (kh == 0) {
#pragma unroll
    for (int jq = 0; jq < 2; ++jq)
#pragma unroll
      for (int dt = 0; dt < 4; ++dt)
#pragma unroll
        for (int r = 0; r < 4; ++r)
          Ob[(16 * dt + 4 * quad + r) * 33 + 16 * jq + l15] = oacc[jq][dt][r];
  }
  __syncthreads();
  if (kh == 1) {
#pragma unroll
    for (int jq = 0; jq < 2; ++jq)
#pragma unroll
      for (int dt = 0; dt < 4; ++dt)
#pragma unroll
        for (int r = 0; r < 4; ++r)
          Ob[(16 * dt + 4 * quad + r) * 33 + 16 * jq + l15] += oacc[jq][dt][r];
  }
  if (tid < 64) {
    int ql = tid & 31, qh2 = tid >> 5;
    Lq[tid] = Lpart[qh2 * 64 + ql] + Lpart[qh2 * 64 + 32 + ql];
  }
  __syncthreads();

  // epilogue: O rows q = 16jq+4quad+r (jq 0..3), cols d = 16w+l15
  const int d = 16 * w + l15;
#pragma unroll
  for (int jq = 0; jq < 4; ++jq) {
    const float* Osrc = (jq < 2) ? OA : OB;
#pragma unroll
    for (int r = 0; r < 4; ++r) {
      int qloc = 16 * jq + 4 * quad + r;
      float ov = Osrc[d * 33 + (qloc & 31)];
      float lv = Lq[qloc];
      float gv = b2f(((const unsigned short*)gc)[
          ((size_t)((b * 16 + h) * 1024) + qt * 64 + qloc) * 64 + d]);
      size_t row = (size_t)(b * NN + qt * 64 + qloc);
      gated[row * 1024 + h * 64 + d] = f2b(ov / lv * gv);
    }
  }
}

// ---------------------------------------------------------------------------
extern "C" void kernel_launch(void* const* d_in, const int* in_sizes, int n_in,
                              void* d_out, int out_size, void* d_ws,
                              size_t ws_size, hipStream_t stream) {
  const float* x = (const float*)d_in[0];
  const float* Wq = (const float*)d_in[1];
  const float* Wkv = (const float*)d_in[2];
  const float* Wg = (const float*)d_in[3];
  const float* bg = (const float*)d_in[4];
  const float* Wo = (const float*)d_in[5];
  float* out = (float*)d_out;

  // ws layout (short elems): ~36.6 MB total
  short* ws = (short*)d_ws;
  short* xb = ws;                     // 4.19M (x bf16; later aliased as gated)
  short* WcT = xb + 4194304;          // 2.62M (W^T combined: q|g|kv rows)
  short* WoT = WcT + 2621440;         // 1.05M
  short* qc = WoT + 1048576;          // 4.19M  q[b,h,tok,d]
  short* gc = qc + 4194304;           // 4.19M  gate[b,h,tok,d]
  short* kc = gc + 4194304;           // 1.05M  K fragment-packed
  short* vtw = kc + 1048576;          // 1.05M  V fragment-packed
  float* bias_f32 = (float*)(vtw + 1048576);  // 2560 f32

  dim3 blk(256);
  // weight transposes + bias + x-convert, one dispatch
  transpose_all<<<dim3(16, 16, 6), blk, 0, stream>>>(Wq, Wkv, Wg, Wo, bg, x,
                                                     WcT, WoT, bias_f32, xb);
  // fused q|gate|kv projection (outputs diverted to packed layouts)
  gemm_proj<<<dim3(20, 32), blk, 0, stream>>>(xb, WcT, bias_f32, qc, gc, kc, vtw);
  // attention + gate -> gated (aliases xb; xb no longer needed)
  attn_mfma15<<<dim3(16, 64), blk, 0, stream>>>(qc, gc, kc, vtw, (unsigned short*)xb);
  // output projection
  gemm_out<<<dim3(16, 64), blk, 0, stream>>>(xb, WoT, out);
}

// Round 15
// 166.773 us; speedup vs baseline: 1.0278x; 1.0181x over previous
//
#include <hip/hip_runtime.h>
#include <hip/hip_bf16.h>
#include <stdint.h>

#define BB 4
#define NN 1024
#define DD 1024
#define HH 16
#define HDIM 64
#define KVHH 4
#define MM (BB * NN)  // 4096 token rows

typedef __hip_bfloat16 bf16;
typedef __attribute__((ext_vector_type(8))) short bf16x8;  // 8 bf16 = 4 VGPR
typedef __attribute__((ext_vector_type(4))) short bf16x4;  // 4 bf16 = 2 VGPR
typedef __attribute__((ext_vector_type(4))) float f32x4;

__device__ __forceinline__ float b2f(unsigned short u) {
  return __uint_as_float(((unsigned)u) << 16);
}
__device__ __forceinline__ unsigned short f2b(float x) {
  bf16 h = __float2bfloat16(x);
  unsigned short u;
  __builtin_memcpy(&u, &h, 2);
  return u;
}
__device__ __forceinline__ f32x4 mfma16(bf16x8 a, bf16x8 b, f32x4 c) {
  return __builtin_amdgcn_mfma_f32_16x16x32_bf16(a, b, c, 0, 0, 0);
}
// K=16 MFMA: B-fragment layout (col=l15, k=quad*4+i) matches the K=32 MFMA's
// C layout (col=l15, row=quad*4+r) -> S output feeds PV directly, in-register.
// (Correctness HW-verified r12-r24: absmax identical across all rounds.)
__device__ __forceinline__ f32x4 mfma16k16(bf16x4 a, bf16x4 b, f32x4 c) {
#if __has_builtin(__builtin_amdgcn_mfma_f32_16x16x16bf16_1k)
  return __builtin_amdgcn_mfma_f32_16x16x16bf16_1k(a, b, c, 0, 0, 0);
#else
  asm("s_nop 1\n\tv_mfma_f32_16x16x16_bf16 %0, %1, %2, %0"
      : "+v"(c)
      : "v"(a), "v"(b));
  return c;
#endif
}
__device__ __forceinline__ bf16x4 vlo(bf16x8 v) {
  return __builtin_shufflevector(v, v, 0, 1, 2, 3);
}
__device__ __forceinline__ bf16x4 vhi(bf16x8 v) {
  return __builtin_shufflevector(v, v, 4, 5, 6, 7);
}
__device__ __forceinline__ void gl_lds16(const short* g, short* l) {
  __builtin_amdgcn_global_load_lds(
      (const __attribute__((address_space(1))) unsigned*)g,
      (__attribute__((address_space(3))) unsigned*)l, 16, 0, 0);
}

// ---------------------------------------------------------------------------
// z=0..3: weight transposes W (K x N fp32) -> WT (N x K bf16), 64x64 tiles.
// z=4: combined bias build. z=5: x fp32 -> bf16 convert.
// r25: LDS pad stride 68 -> 66 shorts. With 68 (34 dw), 16*34 % 32 == 0, so
// all four k16 groups of the transpose-read alias the same bank: 8 lanes/bank
// (4-way beyond the free 2) on 16 scalar reads/thread. 66 (33 dw, odd) gives
// 16*33 % 32 == 16 -> groups split 2+2 -> ~2-way-beyond-free (m136: 2.9->1.5x).
// ---------------------------------------------------------------------------
__global__ __launch_bounds__(256) void transpose_all(
    const float* __restrict__ Wq, const float* __restrict__ Wkv,
    const float* __restrict__ Wg, const float* __restrict__ Wo,
    const float* __restrict__ bg, const float* __restrict__ x,
    short* __restrict__ WcT, short* __restrict__ WoT,
    float* __restrict__ bias, short* __restrict__ xb) {
  const int z = blockIdx.z;
  if (z == 4) {  // combined bias: [0,1024)=0, [1024,2048)=bg, [2048,2560)=0
    if (blockIdx.y == 0 && blockIdx.x < 10) {
      int i = blockIdx.x * 256 + threadIdx.x;
      if (i < 2560) bias[i] = (i >= 1024 && i < 2048) ? bg[i - 1024] : 0.f;
    }
    return;
  }
  if (z == 5) {  // x convert: 256 blocks x 256 threads x 16 float4
    int base = (blockIdx.y * 16 + blockIdx.x) * 256 + threadIdx.x;
#pragma unroll
    for (int it = 0; it < 16; ++it) {
      int i = base + it * 65536;
      float4 v = *(const float4*)&x[(size_t)i * 4];
      ushort4 o;
      o.x = f2b(v.x); o.y = f2b(v.y); o.z = f2b(v.z); o.w = f2b(v.w);
      *(ushort4*)&xb[(size_t)i * 4] = o;
    }
    return;
  }
  const float* W;
  short* WT;
  int N = 1024;
  const int K = 1024;
  if (z == 0) { W = Wq; WT = WcT; }
  else if (z == 1) { W = Wg; WT = WcT + 1048576; }
  else if (z == 2) {
    W = Wkv; WT = WcT + 2097152; N = 512;
    if (blockIdx.x >= 8) return;  // uniform early-out, before any sync
  } else { W = Wo; WT = WoT; }

  __shared__ short T[64 * 66];
  const int tid = threadIdx.x;
  const int n0 = blockIdx.x * 64, k0 = blockIdx.y * 64;
  {
    int i0 = tid >> 4, j4 = (tid & 15) * 4;
#pragma unroll
    for (int ii = 0; ii < 4; ++ii) {
      int i = i0 + 16 * ii;
      float4 w = *(const float4*)&W[(size_t)(k0 + i) * N + n0 + j4];
      ushort4 o;
      o.x = f2b(w.x); o.y = f2b(w.y); o.z = f2b(w.z); o.w = f2b(w.w);
      *(ushort4*)&T[i * 66 + j4] = o;
    }
  }
  __syncthreads();
  {
    int n = tid >> 2, k16 = (tid & 3) * 16;
    short tmp[16];
#pragma unroll
    for (int kk = 0; kk < 16; ++kk) tmp[kk] = T[(k16 + kk) * 66 + n];
    short* dst = WT + (size_t)(n0 + n) * K + k0 + k16;
#pragma unroll
    for (int s = 0; s < 16; s += 4) *(ushort4*)&dst[s] = *(const ushort4*)&tmp[s];
  }
}

// ---------------------------------------------------------------------------
// Fused projection GEMM (r19-proven 128x128, REVERTED from r24's counted-
// vmcnt triple-buffer which regressed ~2us — 2nd null on T4-graft; consistent
// with guide: counted vmcnt pays only inside a full 8-phase interleave).
// Grid 20x32, 4 waves = 2x2 of (64m x 64n), acc[4][4]=64 AGPR, BK=32,
// dbuf gl_lds. (256,3). + XCD swizzle.
// ---------------------------------------------------------------------------
__global__ __launch_bounds__(256, 3) void gemm_proj(
    const short* __restrict__ A, const short* __restrict__ WT,
    const float* __restrict__ bias, short* __restrict__ qc,
    short* __restrict__ gc, short* __restrict__ kc, short* __restrict__ vt) {
  __shared__ short As[2][128 * 32];
  __shared__ short Bs[2][128 * 32];
  const int tid = threadIdx.x;
  const int wave = tid >> 6, lane = tid & 63, l15 = lane & 15, quad = lane >> 4;
  const int bid0 = blockIdx.x + blockIdx.y * 20;
  const int swz = (bid0 & 7) * 80 + (bid0 >> 3);  // XCD chunk swizzle
  const int bx = swz % 20, by = swz / 20;
  const int m0 = by * 128, n0 = bx * 128;
  const int wm = (wave & 1) * 64, wn = (wave >> 1) * 64;
  const int arow = tid >> 2, ac = (tid & 3) * 8;
  const short* asrc = A + (size_t)(m0 + arow) * 1024 + ac;
  const short* bsrc = WT + (size_t)(n0 + arow) * 1024 + ac;

  gl_lds16(asrc, &As[0][wave * 512]);
  gl_lds16(asrc + 64 * 1024, &As[0][2048 + wave * 512]);
  gl_lds16(bsrc, &Bs[0][wave * 512]);
  gl_lds16(bsrc + 64 * 1024, &Bs[0][2048 + wave * 512]);

  f32x4 acc[4][4] = {};
  for (int k = 0; k < 32; ++k) {
    const int cur = k & 1;
    __syncthreads();  // stage(k) landed; iter k-1 LDS reads drained
    if (k < 31) {
      const short* ap = asrc + (k + 1) * 32;
      const short* bp = bsrc + (k + 1) * 32;
      gl_lds16(ap, &As[1 - cur][wave * 512]);
      gl_lds16(ap + 64 * 1024, &As[1 - cur][2048 + wave * 512]);
      gl_lds16(bp, &Bs[1 - cur][wave * 512]);
      gl_lds16(bp + 64 * 1024, &Bs[1 - cur][2048 + wave * 512]);
    }
    bf16x8 af[4], bfr[4];
#pragma unroll
    for (int i = 0; i < 4; ++i)
      af[i] = *(const bf16x8*)&As[cur][(wm + 16 * i + l15) * 32 + quad * 8];
#pragma unroll
    for (int j = 0; j < 4; ++j)
      bfr[j] = *(const bf16x8*)&Bs[cur][(wn + 16 * j + l15) * 32 + quad * 8];
#pragma unroll
    for (int i = 0; i < 4; ++i)
#pragma unroll
      for (int j = 0; j < 4; ++j) acc[i][j] = mfma16(af[i], bfr[j], acc[i][j]);
  }

  const int reg = (n0 + wn) >> 6;  // head-slot 0..39, WAVE-uniform
  if (reg < 16) {  // q: pre-scale by 0.125*log2e (softmax fold)
#pragma unroll
    for (int j = 0; j < 4; ++j) {
      int d = 16 * j + l15;
#pragma unroll
      for (int i = 0; i < 4; ++i)
#pragma unroll
        for (int r = 0; r < 4; ++r) {
          int row = m0 + wm + 16 * i + quad * 4 + r;
          int b = row >> 10, tok = row & 1023;
          ((unsigned short*)qc)[((size_t)((b * 16 + reg) * 1024 + tok)) * 64 + d] =
              f2b(acc[i][j][r] * 0.18033688f);
        }
    }
  } else if (reg < 32) {  // gate (+bias)
#pragma unroll
    for (int j = 0; j < 4; ++j) {
      int d = 16 * j + l15;
      float bv = bias[n0 + wn + d];
#pragma unroll
      for (int i = 0; i < 4; ++i)
#pragma unroll
        for (int r = 0; r < 4; ++r) {
          int row = m0 + wm + 16 * i + quad * 4 + r;
          int b = row >> 10, tok = row & 1023;
          ((unsigned short*)gc)[((size_t)((b * 16 + reg - 16) * 1024 + tok)) * 64 + d] =
              f2b(acc[i][j][r] + bv);
        }
    }
  } else if (reg < 36) {  // K fragment-packed
    int kvh = reg - 32;
#pragma unroll
    for (int j = 0; j < 4; ++j) {
      int d = 16 * j + l15;
      int dh = d >> 5, dq = (d >> 3) & 3, di = d & 7;
#pragma unroll
      for (int i = 0; i < 4; ++i)
#pragma unroll
        for (int r = 0; r < 4; ++r) {
          int row = m0 + wm + 16 * i + quad * 4 + r;
          int b = row >> 10, tok = row & 1023;
          int kt = tok >> 6, kh = (tok >> 5) & 1, k32 = tok & 31;
          int ksub = k32 >> 4, kl = k32 & 15;
          size_t koff = (size_t)(b * 4 + kvh) * 65536 +
                        (size_t)((kt * 2 + kh) * 2048 + (ksub * 2 + dh) * 512 +
                                 (dq * 16 + kl) * 8 + di);
          ((unsigned short*)kc)[koff] = f2b(acc[i][j][r]);
        }
    }
  } else {  // V fragment-packed (4 consecutive r -> one ushort4)
    int kvh = reg - 36;
#pragma unroll
    for (int j = 0; j < 4; ++j) {
      int dt = j;  // d = 16j + l15 -> dt = j, dl = l15
#pragma unroll
      for (int i = 0; i < 4; ++i) {
        int row0 = m0 + wm + 16 * i + quad * 4;
        int b = row0 >> 10, tok0 = row0 & 1023;
        int kt = tok0 >> 6, kh = (tok0 >> 5) & 1, isub = (tok0 >> 4) & 1;
        size_t voff = (size_t)(b * 4 + kvh) * 65536 +
                      (size_t)((kt * 2 + kh) * 2048 + (isub * 2 + (dt >> 1)) * 512 +
                               (quad * 16 + l15) * 8 + (dt & 1) * 4);
        ushort4 o;
        o.x = f2b(acc[i][j][0]);
        o.y = f2b(acc[i][j][1]);
        o.z = f2b(acc[i][j][2]);
        o.w = f2b(acc[i][j][3]);
        *(ushort4*)&((unsigned short*)vt)[voff] = o;
      }
    }
  }
}

// ---------------------------------------------------------------------------
// Output-projection GEMM (r21): 64x64 tile, BK=64 as two [64][32] sub-tiles,
// 1024 blocks = 4/CU, 16 barrier-steps at 8 MFMA each. + XCD swizzle.
// At the 343 TF 64^2-structure ceiling (m92); larger tiles lose occupancy
// at N=1024 (r18/r19 measured) — treat as at practical ceiling.
// ---------------------------------------------------------------------------
__global__ __launch_bounds__(256, 4) void gemm_out(
    const short* __restrict__ A, const short* __restrict__ WT,
    float* __restrict__ Cout) {
  __shared__ short As[2][2][64 * 32];
  __shared__ short Bs[2][2][64 * 32];
  const int tid = threadIdx.x;
  const int wave = tid >> 6, lane = tid & 63, l15 = lane & 15, quad = lane >> 4;
  const int bid0 = blockIdx.x + blockIdx.y * 16;
  const int swz = (bid0 & 7) * 128 + (bid0 >> 3);  // nwg=1024, cpx=128
  const int m0 = (swz >> 4) * 64, n0 = (swz & 15) * 64;
  const int wm = (wave & 1) * 32, wn = (wave >> 1) * 32;
  const int arow = tid >> 2, ac = (tid & 3) * 8;
  const short* asrc = A + (size_t)(m0 + arow) * 1024 + ac;
  const short* bsrc = WT + (size_t)(n0 + arow) * 1024 + ac;

  // stage K-step 0: cols 0..63 as two 32-col subs (each the proven layout)
  gl_lds16(asrc, &As[0][0][wave * 512]);
  gl_lds16(asrc + 32, &As[0][1][wave * 512]);
  gl_lds16(bsrc, &Bs[0][0][wave * 512]);
  gl_lds16(bsrc + 32, &Bs[0][1][wave * 512]);

  f32x4 acc[2][2] = {};
  for (int k = 0; k < 16; ++k) {
    const int cur = k & 1;
    __syncthreads();  // stage(k) landed; iter k-1 LDS reads drained
    if (k < 15) {
      const short* ap = asrc + (k + 1) * 64;
      const short* bp = bsrc + (k + 1) * 64;
      gl_lds16(ap, &As[1 - cur][0][wave * 512]);
      gl_lds16(ap + 32, &As[1 - cur][1][wave * 512]);
      gl_lds16(bp, &Bs[1 - cur][0][wave * 512]);
      gl_lds16(bp + 32, &Bs[1 - cur][1][wave * 512]);
    }
#pragma unroll
    for (int s = 0; s < 2; ++s) {
      bf16x8 af[2], bfr[2];
#pragma unroll
      for (int i = 0; i < 2; ++i)
        af[i] = *(const bf16x8*)&As[cur][s][(wm + 16 * i + l15) * 32 + quad * 8];
#pragma unroll
      for (int j = 0; j < 2; ++j)
        bfr[j] = *(const bf16x8*)&Bs[cur][s][(wn + 16 * j + l15) * 32 + quad * 8];
#pragma unroll
      for (int i = 0; i < 2; ++i)
#pragma unroll
        for (int j = 0; j < 2; ++j) acc[i][j] = mfma16(af[i], bfr[j], acc[i][j]);
    }
  }
#pragma unroll
  for (int j = 0; j < 2; ++j) {
    int col = n0 + wn + 16 * j + l15;
#pragma unroll
    for (int i = 0; i < 2; ++i) {
#pragma unroll
      for (int r = 0; r < 4; ++r) {
        int row = m0 + wm + 16 * i + quad * 4 + r;
        Cout[(size_t)row * 1024 + col] = acc[i][j][r];
      }
    }
  }
}

// ---------------------------------------------------------------------------
// MFMA flash attention + gate (r20): LDS-shared K/V staging, 2x2 wave split,
// in-register P->PV, OA/OB alias dead KV LDS. 4 blocks/CU. UNCHANGED.
// ---------------------------------------------------------------------------
__global__ __launch_bounds__(256, 4) void attn_mfma15(
    const short* __restrict__ qc, const short* __restrict__ gc,
    const short* __restrict__ kc, const short* __restrict__ vt,
    unsigned short* __restrict__ gated) {
  __shared__ short KV[2][8192];  // [buf][ K 4096 sh | V 4096 sh ] = 32 KB
  __shared__ float Lpart[4 * 32];
  __shared__ float Lq[64];
  float* OA = (float*)&KV[0][0];  // aliased AFTER main loop (barrier-fenced)
  float* OB = OA + 64 * 33;
  const int tid = threadIdx.x;
  const int w = tid >> 6, lane = tid & 63, l15 = lane & 15, quad = lane >> 4;
  const int qh = w >> 1, kh = w & 1;
  const int bid0 = blockIdx.x + blockIdx.y * 16;
  const int swz = (bid0 & 7) * 128 + (bid0 >> 3);  // nwg=1024, cpx=128
  const int qt = swz & 15, bh = swz >> 4;
  const int b = bh >> 4, h = bh & 15, kvh = h >> 2;

  // Q B-frags: col q = qt*64 + qh*32 + 16jq + l15, k = d = quad*8+i (+32)
  bf16x8 qf[2][2];
#pragma unroll
  for (int jq = 0; jq < 2; ++jq) {
    const short* qp = qc + ((size_t)((b * 16 + h) * 1024) + qt * 64 + qh * 32 +
                            16 * jq + l15) * 64 + quad * 8;
    qf[jq][0] = *(const bf16x8*)qp;
    qf[jq][1] = *(const bf16x8*)(qp + 32);
  }

  const short* kbase = kc + (size_t)(b * 4 + kvh) * 65536;  // + kt*4096
  const short* vbase = vt + (size_t)(b * 4 + kvh) * 65536;
  const int wdst = w * 512;  // wave-uniform LDS dest (64 lanes x 8 sh)

#define STAGE(CUR, KT)                                                         \
  {                                                                            \
    const short* ks = kbase + (size_t)(KT) * 4096;                             \
    const short* vs = vbase + (size_t)(KT) * 4096;                             \
    gl_lds16(ks + tid * 8, &KV[CUR][wdst]);                                    \
    gl_lds16(ks + 2048 + tid * 8, &KV[CUR][2048 + wdst]);                      \
    gl_lds16(vs + tid * 8, &KV[CUR][4096 + wdst]);                             \
    gl_lds16(vs + 2048 + tid * 8, &KV[CUR][6144 + wdst]);                      \
  }

  f32x4 oacc[2][4] = {};  // [jq][dt]: d = 16dt+4quad+r, q = qh*32+16jq+l15
  float ls[2] = {0.f, 0.f};

#define EXPPV8(ST, JQ, WA, WB)                                                 \
  {                                                                            \
    float p0 = exp2f((ST)[0]), p1 = exp2f((ST)[1]);                            \
    float p2 = exp2f((ST)[2]), p3 = exp2f((ST)[3]);                            \
    ls[JQ] += (p0 + p1) + (p2 + p3);                                           \
    bf16x4 pbf;                                                                \
    pbf[0] = (short)f2b(p0);                                                   \
    pbf[1] = (short)f2b(p1);                                                   \
    pbf[2] = (short)f2b(p2);                                                   \
    pbf[3] = (short)f2b(p3);                                                   \
    oacc[JQ][0] = mfma16k16(vlo(WA), pbf, oacc[JQ][0]);                        \
    oacc[JQ][1] = mfma16k16(vhi(WA), pbf, oacc[JQ][1]);                        \
    oacc[JQ][2] = mfma16k16(vlo(WB), pbf, oacc[JQ][2]);                        \
    oacc[JQ][3] = mfma16k16(vhi(WB), pbf, oacc[JQ][3]);                        \
  }

  STAGE(0, 0);
  for (int kt = 0; kt < 16; ++kt) {
    const int cur = kt & 1;
    __syncthreads();  // stage(kt) landed (barrier drains vmcnt)
    if (kt < 15) STAGE(cur ^ 1, kt + 1);
    const short* kl = &KV[cur][kh * 2048 + lane * 8];
    const short* vl = &KV[cur][4096 + kh * 2048 + lane * 8];
    bf16x8 kA0 = *(const bf16x8*)(kl);
    bf16x8 kA1 = *(const bf16x8*)(kl + 512);
    bf16x8 kA2 = *(const bf16x8*)(kl + 1024);
    bf16x8 kA3 = *(const bf16x8*)(kl + 1536);
    bf16x8 w0 = *(const bf16x8*)(vl);
    bf16x8 w1 = *(const bf16x8*)(vl + 512);
    bf16x8 w2 = *(const bf16x8*)(vl + 1024);
    bf16x8 w3 = *(const bf16x8*)(vl + 1536);
    // ---- S keysub0, both jq
    f32x4 s00 = mfma16(kA0, qf[0][0], (f32x4){0.f, 0.f, 0.f, 0.f});
    s00 = mfma16(kA1, qf[0][1], s00);
    f32x4 s10 = mfma16(kA0, qf[1][0], (f32x4){0.f, 0.f, 0.f, 0.f});
    s10 = mfma16(kA1, qf[1][1], s10);
    EXPPV8(s00, 0, w0, w1);
    EXPPV8(s10, 1, w0, w1);
    // ---- S keysub1
    f32x4 s01 = mfma16(kA2, qf[0][0], (f32x4){0.f, 0.f, 0.f, 0.f});
    s01 = mfma16(kA3, qf[0][1], s01);
    f32x4 s11 = mfma16(kA2, qf[1][0], (f32x4){0.f, 0.f, 0.f, 0.f});
    s11 = mfma16(kA3, qf[1][1], s11);
    EXPPV8(s01, 0, w2, w3);
    EXPPV8(s11, 1, w2, w3);
  }
#undef EXPPV8
#undef STAGE

  // l reduction: quad-reduce in-wave (sum over this wave's 512 keys per q)
#pragma unroll
  for (int jq = 0; jq < 2; ++jq) {
    ls[jq] += __shfl_xor(ls[jq], 16);
    ls[jq] += __shfl_xor(ls[jq], 32);
  }
  __syncthreads();  // all KV ds_reads done before OA/OB alias the same LDS
  if (quad == 0) {
#pragma unroll
    for (int jq = 0; jq < 2; ++jq) Lpart[w * 32 + 16 * jq + l15] = ls[jq];
  }
  // cross-wave O reduction: kh=0 waves write their qh buffer; kh=1 waves add.
  float* Ob = qh ? OB : OA;
  if (kh == 0) {
#pragma unroll
    for (int jq = 0; jq < 2; ++jq)
#pragma unroll
      for (int dt = 0; dt < 4; ++dt)
#pragma unroll
        for (int r = 0; r < 4; ++r)
          Ob[(16 * dt + 4 * quad + r) * 33 + 16 * jq + l15] = oacc[jq][dt][r];
  }
  __syncthreads();
  if (kh == 1) {
#pragma unroll
    for (int jq = 0; jq < 2; ++jq)
#pragma unroll
      for (int dt = 0; dt < 4; ++dt)
#pragma unroll
        for (int r = 0; r < 4; ++r)
          Ob[(16 * dt + 4 * quad + r) * 33 + 16 * jq + l15] += oacc[jq][dt][r];
  }
  if (tid < 64) {
    int ql = tid & 31, qh2 = tid >> 5;
    Lq[tid] = Lpart[qh2 * 64 + ql] + Lpart[qh2 * 64 + 32 + ql];
  }
  __syncthreads();

  // epilogue: O rows q = 16jq+4quad+r (jq 0..3), cols d = 16w+l15
  const int d = 16 * w + l15;
#pragma unroll
  for (int jq = 0; jq < 4; ++jq) {
    const float* Osrc = (jq < 2) ? OA : OB;
#pragma unroll
    for (int r = 0; r < 4; ++r) {
      int qloc = 16 * jq + 4 * quad + r;
      float ov = Osrc[d * 33 + (qloc & 31)];
      float lv = Lq[qloc];
      float gv = b2f(((const unsigned short*)gc)[
          ((size_t)((b * 16 + h) * 1024) + qt * 64 + qloc) * 64 + d]);
      size_t row = (size_t)(b * NN + qt * 64 + qloc);
      gated[row * 1024 + h * 64 + d] = f2b(ov / lv * gv);
    }
  }
}

// ---------------------------------------------------------------------------
extern "C" void kernel_launch(void* const* d_in, const int* in_sizes, int n_in,
                              void* d_out, int out_size, void* d_ws,
                              size_t ws_size, hipStream_t stream) {
  const float* x = (const float*)d_in[0];
  const float* Wq = (const float*)d_in[1];
  const float* Wkv = (const float*)d_in[2];
  const float* Wg = (const float*)d_in[3];
  const float* bg = (const float*)d_in[4];
  const float* Wo = (const float*)d_in[5];
  float* out = (float*)d_out;

  // ws layout (short elems): ~36.6 MB total
  short* ws = (short*)d_ws;
  short* xb = ws;                     // 4.19M (x bf16; later aliased as gated)
  short* WcT = xb + 4194304;          // 2.62M (W^T combined: q|g|kv rows)
  short* WoT = WcT + 2621440;         // 1.05M
  short* qc = WoT + 1048576;          // 4.19M  q[b,h,tok,d]
  short* gc = qc + 4194304;           // 4.19M  gate[b,h,tok,d]
  short* kc = gc + 4194304;           // 1.05M  K fragment-packed
  short* vtw = kc + 1048576;          // 1.05M  V fragment-packed
  float* bias_f32 = (float*)(vtw + 1048576);  // 2560 f32

  dim3 blk(256);
  // weight transposes + bias + x-convert, one dispatch
  transpose_all<<<dim3(16, 16, 6), blk, 0, stream>>>(Wq, Wkv, Wg, Wo, bg, x,
                                                     WcT, WoT, bias_f32, xb);
  // fused q|gate|kv projection (outputs diverted to packed layouts)
  gemm_proj<<<dim3(20, 32), blk, 0, stream>>>(xb, WcT, bias_f32, qc, gc, kc, vtw);
  // attention + gate -> gated (aliases xb; xb no longer needed)
  attn_mfma15<<<dim3(16, 64), blk, 0, stream>>>(qc, gc, kc, vtw, (unsigned short*)xb);
  // output projection
  gemm_out<<<dim3(16, 64), blk, 0, stream>>>(xb, WoT, out);
}